// Round 1
// baseline (1007438.477 us; speedup 1.0000x reference)
//
#include <hip/hip_runtime.h>

// ---------------------------------------------------------------------------
// BiLSTM seq2seq + attention + vocab softmax for MI355X (gfx950).
// B=4, T=128, E=512, H=512, D=1024, V=32000.
// Round 4: XCD-island LSTM exchange.
//  - The per-step h handoff previously used agent-scope (sc0+sc1) atomics ->
//    every publish/poll round-tripped through MALL. Workers are now ELECTED
//    onto a single XCD via HW_REG_XCC_ID + atomic ranking; the exchange then
//    uses sc0-only loads (XCD L2 hit) and write-through stores. Tagged-word
//    protocol unchanged (self-validating, relaxed, no fences).
//  - Election is deadlock-safe: 512 candidates (<= resident slots at
//    __launch_bounds__(256,2)), pigeonhole guarantees one XCD collects 64.
//    Guarded fallback to the old agent-scope path if election times out.
// ---------------------------------------------------------------------------

typedef __attribute__((ext_vector_type(8))) short bf16x8;   // 8 bf16 = 4 VGPRs
typedef __attribute__((ext_vector_type(4))) float f32x4;

__device__ __forceinline__ short f2bf(float f) {  // RNE fp32 -> bf16
  unsigned u = __builtin_bit_cast(unsigned, f);
  u += 0x7fffu + ((u >> 16) & 1u);
  return (short)(u >> 16);
}
__device__ __forceinline__ float b2f(short s) {
  unsigned u = ((unsigned)(unsigned short)s) << 16;
  return __builtin_bit_cast(float, u);
}
__device__ __forceinline__ float sigf(float x) { return 1.f / (1.f + __expf(-x)); }
__device__ __forceinline__ float tanhf_fast(float x) {
  x = fminf(fmaxf(x, -15.f), 15.f);
  float e = __expf(2.f * x);
  return (e - 1.f) / (e + 1.f);
}

// relaxed agent-scope atomics (sc0 sc1 -> MALL). Used for election + fallback.
__device__ __forceinline__ unsigned ld_coh(const unsigned* p) {
  return __hip_atomic_load(p, __ATOMIC_RELAXED, __HIP_MEMORY_SCOPE_AGENT);
}
__device__ __forceinline__ void st_coh(unsigned* p, unsigned v) {
  __hip_atomic_store(p, v, __ATOMIC_RELAXED, __HIP_MEMORY_SCOPE_AGENT);
}

// ---- XCD-island ops: sc0 only (bypass L1, served by the local XCD L2) -----
__device__ __forceinline__ void st_sc0(unsigned* p, unsigned v) {
  asm volatile("global_store_dword %0, %1, off sc0" :: "v"(p), "v"(v) : "memory");
}
template<bool ISL>
__device__ __forceinline__ void pub(unsigned* p, unsigned v) {
  if (ISL) st_sc0(p, v); else st_coh(p, v);
}

// 16 sc0 dword loads at stride 1024B from p; waitcnt INSIDE the asm (rule 18).
__device__ __forceinline__ void ld16_sc0(const unsigned* p, unsigned* v) {
  const unsigned *p0 = p, *p1 = p + 1024, *p2 = p + 2048, *p3 = p + 3072;
  asm volatile(
      "global_load_dword %0,  %16, off sc0\n\t"
      "global_load_dword %1,  %16, off offset:1024 sc0\n\t"
      "global_load_dword %2,  %16, off offset:2048 sc0\n\t"
      "global_load_dword %3,  %16, off offset:3072 sc0\n\t"
      "global_load_dword %4,  %17, off sc0\n\t"
      "global_load_dword %5,  %17, off offset:1024 sc0\n\t"
      "global_load_dword %6,  %17, off offset:2048 sc0\n\t"
      "global_load_dword %7,  %17, off offset:3072 sc0\n\t"
      "global_load_dword %8,  %18, off sc0\n\t"
      "global_load_dword %9,  %18, off offset:1024 sc0\n\t"
      "global_load_dword %10, %18, off offset:2048 sc0\n\t"
      "global_load_dword %11, %18, off offset:3072 sc0\n\t"
      "global_load_dword %12, %19, off sc0\n\t"
      "global_load_dword %13, %19, off offset:1024 sc0\n\t"
      "global_load_dword %14, %19, off offset:2048 sc0\n\t"
      "global_load_dword %15, %19, off offset:3072 sc0\n\t"
      "s_waitcnt vmcnt(0)"
      : "=&v"(v[0]), "=&v"(v[1]), "=&v"(v[2]), "=&v"(v[3]),
        "=&v"(v[4]), "=&v"(v[5]), "=&v"(v[6]), "=&v"(v[7]),
        "=&v"(v[8]), "=&v"(v[9]), "=&v"(v[10]), "=&v"(v[11]),
        "=&v"(v[12]), "=&v"(v[13]), "=&v"(v[14]), "=&v"(v[15])
      : "v"(p0), "v"(p1), "v"(p2), "v"(p3)
      : "memory");
}
__device__ __forceinline__ void ld8_sc0(const unsigned* p, unsigned* v) {
  const unsigned *p0 = p, *p1 = p + 1024;
  asm volatile(
      "global_load_dword %0, %8, off sc0\n\t"
      "global_load_dword %1, %8, off offset:1024 sc0\n\t"
      "global_load_dword %2, %8, off offset:2048 sc0\n\t"
      "global_load_dword %3, %8, off offset:3072 sc0\n\t"
      "global_load_dword %4, %9, off sc0\n\t"
      "global_load_dword %5, %9, off offset:1024 sc0\n\t"
      "global_load_dword %6, %9, off offset:2048 sc0\n\t"
      "global_load_dword %7, %9, off offset:3072 sc0\n\t"
      "s_waitcnt vmcnt(0)"
      : "=&v"(v[0]), "=&v"(v[1]), "=&v"(v[2]), "=&v"(v[3]),
        "=&v"(v[4]), "=&v"(v[5]), "=&v"(v[6]), "=&v"(v[7])
      : "v"(p0), "v"(p1)
      : "memory");
}

// ---- election: rank this block among its XCD's arrivals -------------------
// e[0..7] per-XCD counters, e[8] winner (xcd+1). All zeroed by prep.
// Returns: >=0 worker slice (island mode), -1 loser (exit), -2 fallback.
__device__ __forceinline__ int elect(unsigned* e, int nwork) {
  __shared__ unsigned sh_w, sh_r, sh_x;
  if (threadIdx.x == 0) {
    unsigned xcd;
    asm volatile("s_getreg_b32 %0, hwreg(HW_REG_XCC_ID)" : "=s"(xcd));
    xcd &= 7u;
    unsigned r = atomicAdd(e + xcd, 1u);
    if ((int)r == nwork - 1) atomicCAS(e + 8, 0u, xcd + 1u);
    unsigned w; int g = 0;
    while (!(w = ld_coh(e + 8)) && ++g < (1 << 12)) __builtin_amdgcn_s_sleep(16);
    sh_w = w; sh_r = r; sh_x = xcd;
  }
  __syncthreads();
  if (sh_w == 0) return -2;  // election timed out -> agent-scope fallback
  return (sh_x == sh_w - 1 && (int)sh_r < nwork) ? (int)sh_r : -1;
}

// ---- workspace layout -----------------------------------------------------
#define OFF_HBF   ((size_t)0)                       // enc fwd h [2][4*512] u32 tagged
#define OFF_HBB   (OFF_HBF + 2*2048*4)              // enc bwd h
#define OFF_HBD   (OFF_HBB + 2*2048*4)              // dec h [2][4*1024] u32 tagged
#define OFF_ENCX  (OFF_HBD + 2*4096*4)              // enc_x swz [64][512][8] bf16
#define OFF_DECX  (OFF_ENCX + (size_t)64*512*8*2)
#define OFF_WXF   (OFF_DECX + (size_t)64*512*8*2)   // Wx_f swz [64][2048][8]
#define OFF_WXB   (OFF_WXF + (size_t)512*2048*2)
#define OFF_WXD   (OFF_WXB + (size_t)512*2048*2)    // Wx_d swz [64][4096][8]
#define OFF_WOS   (OFF_WXD + (size_t)512*4096*2)    // Wo  swz [128][32000][8]
#define OFF_XWF   (OFF_WOS + (size_t)1024*32000*2)  // xw_f fp32 [512][2048]
#define OFF_XWB   (OFF_XWF + (size_t)512*2048*4)
#define OFF_XWD   (OFF_XWB + (size_t)512*2048*4)    // xw_d fp32 [512][4096]
#define OFF_ENCO  (OFF_XWD + (size_t)512*4096*4)    // enc_out fp32 [4][128][1024]
#define OFF_ENCT  (OFF_ENCO + (size_t)4*128*1024*4) // enc_out^T fp32 [4][1024][128]
#define OFF_DECO  (OFF_ENCT + (size_t)4*128*1024*4) // dec_out fp32 [4][128][1024]
#define OFF_ATTN  (OFF_DECO + (size_t)4*128*1024*4) // attn swz [128][512][8] bf16
#define OFF_LOG   (OFF_ATTN + (size_t)128*512*8*2)  // logits bf16 [512][32000]
#define OFF_ELEC  (OFF_LOG + (size_t)512*32000*2)   // election: [16] enc, [16] dec
#define WS_NEED   (OFF_ELEC + 32*4)

// ---- shared bodies --------------------------------------------------------
__device__ __forceinline__ void gather_body(const int* seq, const float* emb,
                                            short* dst, int bx, int by) {
  int m  = by * 64 + (threadIdx.x & 63);
  int e8 = bx * 4 + (threadIdx.x >> 6);
  int id = seq[m];
  const float* src = emb + (size_t)id * 512 + e8 * 8;
  bf16x8 v;
#pragma unroll
  for (int j = 0; j < 8; ++j) v[j] = f2bf(src[j]);
  *(bf16x8*)(dst + ((size_t)e8 * 512 + m) * 8) = v;
}

__device__ __forceinline__ void swz_body(const float* W, short* dst, int N,
                                         int k8, int n) {
  const float* src = W + (size_t)k8 * 8 * N + n;
  bf16x8 v;
#pragma unroll
  for (int j = 0; j < 8; ++j) v[j] = f2bf(src[(size_t)j * N]);
  *(bf16x8*)(dst + ((size_t)k8 * N + n) * 8) = v;
}

// LDS-free bf16 MFMA GEMM on [K/8][M][8]-swizzled operands; 128x128/block.
__device__ __forceinline__ void gemm_body(const short* __restrict__ A,
                                          const short* __restrict__ B,
                                          float* Cf, short* Cb,
                                          int M, int N, int K,
                                          int bx, int by, bool bf16out) {
  const int wv = threadIdx.x >> 6, lane = threadIdx.x & 63;
  const int q = lane >> 4, l15 = lane & 15;
  const int m0 = by * 128 + (wv >> 1) * 64;
  const int n0 = bx * 128 + (wv & 1) * 64;
  f32x4 acc[4][4];
#pragma unroll
  for (int i = 0; i < 4; ++i)
#pragma unroll
    for (int j = 0; j < 4; ++j) acc[i][j] = (f32x4){0.f, 0.f, 0.f, 0.f};
  const int KS = K >> 5;
  for (int ks = 0; ks < KS; ++ks) {
    const size_t k8 = (size_t)(ks * 4 + q);
    const short* Ap = A + (k8 * M + m0 + l15) * 8;
    const short* Bp = B + (k8 * N + n0 + l15) * 8;
    bf16x8 av[4], bv[4];
#pragma unroll
    for (int i = 0; i < 4; ++i) av[i] = *(const bf16x8*)(Ap + i * 128);
#pragma unroll
    for (int j = 0; j < 4; ++j) bv[j] = *(const bf16x8*)(Bp + j * 128);
#pragma unroll
    for (int i = 0; i < 4; ++i)
#pragma unroll
      for (int j = 0; j < 4; ++j)
        acc[i][j] = __builtin_amdgcn_mfma_f32_16x16x32_bf16(av[i], bv[j], acc[i][j], 0, 0, 0);
  }
#pragma unroll
  for (int i = 0; i < 4; ++i)
#pragma unroll
    for (int j = 0; j < 4; ++j)
#pragma unroll
      for (int r = 0; r < 4; ++r) {
        size_t idx = (size_t)(m0 + i * 16 + q * 4 + r) * N + (n0 + j * 16 + l15);
        if (bf16out) Cb[idx] = f2bf(acc[i][j][r]);
        else         Cf[idx] = acc[i][j][r];
      }
}

// ---- prep: gathers + Wx swizzles + election-counter zeroing ---------------
__global__ __launch_bounds__(256) void prep(
    const int* __restrict__ iseq, const int* __restrict__ oseq,
    const float* __restrict__ enc_emb, const float* __restrict__ dec_emb,
    const float* __restrict__ Wx_f, const float* __restrict__ Wx_b,
    const float* __restrict__ Wx_d,
    short* encx, short* decx, short* wxf_s, short* wxb_s, short* wxd_s,
    unsigned* elec) {
  int bid = blockIdx.x;
  if (bid == 0 && threadIdx.x < 32) elec[threadIdx.x] = 0u;  // enc + dec sets
  if (bid < 128)        { gather_body(iseq, enc_emb, encx, bid & 15, bid >> 4); return; }
  if (bid < 256)        { int s = bid - 128;  gather_body(oseq, dec_emb, decx, s & 15, s >> 4); return; }
  if (bid < 768)        { int s = bid - 256;  swz_body(Wx_f, wxf_s, 2048, s >> 3, (s & 7) * 256 + threadIdx.x); return; }
  if (bid < 1280)       { int s = bid - 768;  swz_body(Wx_b, wxb_s, 2048, s >> 3, (s & 7) * 256 + threadIdx.x); return; }
  { int s = bid - 1280; swz_body(Wx_d, wxd_s, 4096, s >> 4, (s & 15) * 256 + threadIdx.x); }
}

// ---- xw GEMMs for both encoder directions in one launch -------------------
__global__ __launch_bounds__(256) void xw_enc_gemm(
    const short* __restrict__ encx, const short* __restrict__ wxf_s,
    const short* __restrict__ wxb_s, float* xw_f, float* xw_b) {
  gemm_body(encx, blockIdx.z ? wxb_s : wxf_s, blockIdx.z ? xw_b : xw_f,
            nullptr, 512, 2048, 512, blockIdx.x, blockIdx.y, false);
}

// ---- encoder LSTM body (templated on island mode) -------------------------
template<bool ISL>
__device__ __forceinline__ void lstm_enc_body(
    const float* __restrict__ Wh_f, const float* __restrict__ Wh_b,
    const float* __restrict__ xw_f, const float* __restrict__ xw_b,
    const float* __restrict__ b_f, const float* __restrict__ b_b,
    unsigned* hb_f, unsigned* hb_b, float* enc_out, float* encT, int slice) {
  const int dir = slice >> 5;
  const int u0  = (slice & 31) * 16;
  const int tid = threadIdx.x;
  const int w = tid >> 6, lane = tid & 63;
  const int q = lane >> 4, l15 = lane & 15;
  const float* Wh   = dir ? Wh_b : Wh_f;
  const float* xw   = dir ? xw_b : xw_f;
  const float* bias = dir ? b_b : b_f;
  unsigned* hb = dir ? hb_b : hb_f;

  __shared__ short hs[5][520];    // h staged bf16; row 4 = zeros (pad rows)
  __shared__ float zb[4][4][16];  // [gate][b][unit]
  __shared__ float cb[4][16];     // cell state [b][unit]
  if (tid < 64) {
    cb[tid >> 4][tid & 15] = 0.f;
    pub<ISL>(hb + (tid >> 4) * 512 + u0 + (tid & 15), 1u << 16);
  }
  for (int k = tid; k < 520; k += 256) hs[4][k] = 0;

  const int col = w * 512 + u0 + l15;       // gate column in [0,2048)
  const float bcol = bias[col];
  bf16x8 wfrag[16];                          // Wh fragments, live in VGPRs
#pragma unroll
  for (int ks = 0; ks < 16; ++ks) {
    bf16x8 v;
#pragma unroll
    for (int jj = 0; jj < 8; ++jj) {
      int k = ks * 32 + q * 8 + jj;
      v[jj] = f2bf(Wh[(size_t)k * 2048 + col]);
    }
    wfrag[ks] = v;
  }
  const short* hp = hs[(l15 < 4) ? l15 : 4];
  float xwv[4];
  if (q == 0) {
    int tx0 = dir ? 127 : 0;
#pragma unroll
    for (int r = 0; r < 4; ++r) xwv[r] = xw[((size_t)(r * 128 + tx0)) * 2048 + col];
  }
  __syncthreads();

#pragma unroll 1
  for (int t = 0; t < 128; ++t) {
    const unsigned exp_ = (unsigned)(t + 1);
    const unsigned* src = hb + (t & 1) * 2048;
    unsigned v[8];
    bool ok;
    int guard = 0;
    do {
      if (ISL) ld8_sc0(src + tid, v);
      else {
#pragma unroll
        for (int j = 0; j < 8; ++j) v[j] = ld_coh(src + j * 256 + tid);
      }
      ok = true;
#pragma unroll
      for (int j = 0; j < 8; ++j) ok &= ((v[j] >> 16) == exp_);
      if (!ok) __builtin_amdgcn_s_sleep(1);
    } while (!ok && ++guard < (1 << 14));
#pragma unroll
    for (int j = 0; j < 8; ++j) {
      unsigned idx = j * 256 + tid;
      hs[idx >> 9][idx & 511] = (short)(v[j] & 0xffffu);
    }
    __syncthreads();

    f32x4 a0 = (f32x4){0.f, 0.f, 0.f, 0.f}, a1 = a0;
#pragma unroll
    for (int ks = 0; ks < 16; ks += 2) {
      bf16x8 f0 = *(const bf16x8*)(hp + ks * 32 + q * 8);
      bf16x8 f1 = *(const bf16x8*)(hp + (ks + 1) * 32 + q * 8);
      a0 = __builtin_amdgcn_mfma_f32_16x16x32_bf16(f0, wfrag[ks], a0, 0, 0, 0);
      a1 = __builtin_amdgcn_mfma_f32_16x16x32_bf16(f1, wfrag[ks + 1], a1, 0, 0, 0);
    }
    const int tx = dir ? (127 - t) : t;
    if (q == 0) {
#pragma unroll
      for (int r = 0; r < 4; ++r) zb[w][r][l15] = a0[r] + a1[r] + xwv[r] + bcol;
      if (t < 127) {                        // prefetch next step's xw
        int txn = dir ? (126 - t) : (t + 1);
#pragma unroll
        for (int r = 0; r < 4; ++r) xwv[r] = xw[((size_t)(r * 128 + txn)) * 2048 + col];
      }
    }
    __syncthreads();
    if (tid < 64) {
      int b = tid >> 4, u = tid & 15;
      float zi = zb[0][b][u], zf = zb[1][b][u], zg = zb[2][b][u], zo = zb[3][b][u];
      float c = sigf(zf) * cb[b][u] + sigf(zi) * tanhf_fast(zg);
      cb[b][u] = c;
      float h = sigf(zo) * tanhf_fast(c);
      if (t < 127)
        pub<ISL>(hb + ((t + 1) & 1) * 2048 + b * 512 + u0 + u,
                 ((unsigned)(t + 2) << 16) | (unsigned short)f2bf(h));
      int d = dir * 512 + u0 + u;
      enc_out[((size_t)(b * 128 + tx)) * 1024 + d] = h;
      encT[((size_t)(b * 1024 + d)) * 128 + tx] = h;
    }
  }
}

// ---- enc launch: LSTM candidates (0..511) + xw_d GEMM + Wo swizzle --------
__global__ __launch_bounds__(256, 2) void lstm_enc_fused(
    const float* __restrict__ Wh_f, const float* __restrict__ Wh_b,
    const float* __restrict__ xw_f, const float* __restrict__ xw_b,
    const float* __restrict__ b_f, const float* __restrict__ b_b,
    unsigned* hb_f, unsigned* hb_b, float* enc_out, float* encT,
    const short* __restrict__ decx, const short* __restrict__ wxd_s,
    float* xw_d, const float* __restrict__ Wo, short* wo_s, unsigned* elec) {
  const int bid = blockIdx.x;
  const int tid = threadIdx.x;
  if (bid >= 640) {          // Wo swizzle: 16000 blocks, N=32000, 128 k8-rows
    int sb = bid - 640;
    int k8 = sb / 125, nb = sb - k8 * 125;
    swz_body(Wo, wo_s, 32000, k8, nb * 256 + tid);
    return;
  }
  if (bid >= 512) {          // xw_d = decx @ wxd_s : 128 blocks
    int gb = bid - 512;
    gemm_body(decx, wxd_s, xw_d, nullptr, 512, 4096, 512, gb & 31, gb >> 5, false);
    return;
  }
  int slice = elect(elec, 64);
  if (slice >= 0) {
    lstm_enc_body<true>(Wh_f, Wh_b, xw_f, xw_b, b_f, b_b, hb_f, hb_b,
                        enc_out, encT, slice);
    return;
  }
  if (slice == -2 && bid < 64)   // fallback: agent-scope exchange
    lstm_enc_body<false>(Wh_f, Wh_b, xw_f, xw_b, b_f, b_b, hb_f, hb_b,
                         enc_out, encT, bid);
}

// ---- decoder LSTM body ----------------------------------------------------
template<bool ISL>
__device__ __forceinline__ void lstm_dec_body(
    const float* __restrict__ Wh_d, const float* __restrict__ xw_d,
    const float* __restrict__ b_d, const float* __restrict__ enc_out,
    unsigned* hb, float* dec_out, int slice) {
  const int u0  = slice * 16;
  const int tid = threadIdx.x;
  const int w = tid >> 6, lane = tid & 63;
  const int q = lane >> 4, l15 = lane & 15;

  __shared__ short hs[5][1032];   // row 4 = zeros
  __shared__ float zb[4][4][16];
  __shared__ float cb[4][16];
  if (tid < 64) {
    int b = tid >> 4, u = tid & 15;
    cb[b][u] = 0.f;
    float h0 = enc_out[((size_t)(b * 128 + 127)) * 1024 + u0 + u];
    pub<ISL>(hb + b * 1024 + u0 + u, (1u << 16) | (unsigned short)f2bf(h0));
  }
  for (int k = tid; k < 1032; k += 256) hs[4][k] = 0;

  const int col = w * 1024 + u0 + l15;      // gate column in [0,4096)
  const float bcol = b_d[col];
  bf16x8 wfrag[32];
#pragma unroll
  for (int ks = 0; ks < 32; ++ks) {
    bf16x8 v;
#pragma unroll
    for (int jj = 0; jj < 8; ++jj) {
      int k = ks * 32 + q * 8 + jj;
      v[jj] = f2bf(Wh_d[(size_t)k * 4096 + col]);
    }
    wfrag[ks] = v;
  }
  const short* hp = hs[(l15 < 4) ? l15 : 4];
  float xwv[4];
  if (q == 0) {
#pragma unroll
    for (int r = 0; r < 4; ++r) xwv[r] = xw_d[((size_t)(r * 128)) * 4096 + col];
  }
  __syncthreads();

#pragma unroll 1
  for (int t = 0; t < 128; ++t) {
    const unsigned exp_ = (unsigned)(t + 1);
    const unsigned* src = hb + (t & 1) * 4096;
    unsigned v[16];
    bool ok;
    int guard = 0;
    do {
      if (ISL) ld16_sc0(src + tid, v);
      else {
#pragma unroll
        for (int j = 0; j < 16; ++j) v[j] = ld_coh(src + j * 256 + tid);
      }
      ok = true;
#pragma unroll
      for (int j = 0; j < 16; ++j) ok &= ((v[j] >> 16) == exp_);
      if (!ok) __builtin_amdgcn_s_sleep(1);
    } while (!ok && ++guard < (1 << 14));
#pragma unroll
    for (int j = 0; j < 16; ++j) {
      unsigned idx = j * 256 + tid;
      hs[idx >> 10][idx & 1023] = (short)(v[j] & 0xffffu);
    }
    __syncthreads();

    f32x4 a0 = (f32x4){0.f, 0.f, 0.f, 0.f}, a1 = a0;
#pragma unroll
    for (int ks = 0; ks < 32; ks += 2) {
      bf16x8 f0 = *(const bf16x8*)(hp + ks * 32 + q * 8);
      bf16x8 f1 = *(const bf16x8*)(hp + (ks + 1) * 32 + q * 8);
      a0 = __builtin_amdgcn_mfma_f32_16x16x32_bf16(f0, wfrag[ks], a0, 0, 0, 0);
      a1 = __builtin_amdgcn_mfma_f32_16x16x32_bf16(f1, wfrag[ks + 1], a1, 0, 0, 0);
    }
    if (q == 0) {
#pragma unroll
      for (int r = 0; r < 4; ++r) zb[w][r][l15] = a0[r] + a1[r] + xwv[r] + bcol;
      if (t < 127) {
#pragma unroll
        for (int r = 0; r < 4; ++r) xwv[r] = xw_d[((size_t)(r * 128 + t + 1)) * 4096 + col];
      }
    }
    __syncthreads();
    if (tid < 64) {
      int b = tid >> 4, u = tid & 15;
      float zi = zb[0][b][u], zf = zb[1][b][u], zg = zb[2][b][u], zo = zb[3][b][u];
      float c = sigf(zf) * cb[b][u] + sigf(zi) * tanhf_fast(zg);
      cb[b][u] = c;
      float h = sigf(zo) * tanhf_fast(c);
      if (t < 127)
        pub<ISL>(hb + ((t + 1) & 1) * 4096 + b * 1024 + u0 + u,
                 ((unsigned)(t + 2) << 16) | (unsigned short)f2bf(h));
      dec_out[((size_t)(b * 128 + t)) * 1024 + u0 + u] = h;
    }
  }
}

__global__ __launch_bounds__(256, 2) void lstm_dec(
    const float* __restrict__ Wh_d, const float* __restrict__ xw_d,
    const float* __restrict__ b_d, const float* __restrict__ enc_out,
    unsigned* hb, float* dec_out, unsigned* elec) {
  int slice = elect(elec, 64);
  if (slice >= 0) {
    lstm_dec_body<true>(Wh_d, xw_d, b_d, enc_out, hb, dec_out, slice);
    return;
  }
  if (slice == -2 && blockIdx.x < 64)
    lstm_dec_body<false>(Wh_d, xw_d, b_d, enc_out, hb, dec_out, blockIdx.x);
}

// ---- attention: one block per (b,t); writes swizzled bf16 attn ------------
__global__ __launch_bounds__(256) void attention(
    const float* __restrict__ dec_out, const float* __restrict__ enc_out,
    const float* __restrict__ encT, const float* __restrict__ scale,
    short* __restrict__ attn_swz) {
  const int m = blockIdx.x, b = m >> 7, tid = threadIdx.x;
  __shared__ float dec_s[1024], scl_s[1024];
  __shared__ float red[256], wts[128], sred[2];
  for (int d = tid; d < 1024; d += 256) {
    dec_s[d] = dec_out[(size_t)m * 1024 + d];
    scl_s[d] = scale[d];
  }
  __syncthreads();
  const int s = tid & 127, half = tid >> 7;
  float sc = 0.f;
  const float* ep = encT + (size_t)b * 1024 * 128 + s;
  for (int d = half * 512; d < half * 512 + 512; ++d)
    sc += tanhf_fast(dec_s[d] + ep[(size_t)d * 128]) * scl_s[d];
  red[tid] = sc;
  __syncthreads();
  float v = 0.f;
  if (tid < 128) { v = red[tid] + red[tid + 128]; wts[tid] = v; }
  __syncthreads();
  if (tid < 64) {
    float mx = fmaxf(wts[tid], wts[tid + 64]);
    for (int off = 32; off; off >>= 1) mx = fmaxf(mx, __shfl_down(mx, off));
    if (tid == 0) sred[0] = mx;
  }
  __syncthreads();
  const float MX = sred[0];
  if (tid < 128) { v = __expf(v - MX); wts[tid] = v; }
  __syncthreads();
  if (tid < 64) {
    float sm = wts[tid] + wts[tid + 64];
    for (int off = 32; off; off >>= 1) sm += __shfl_down(sm, off);
    if (tid == 0) sred[1] = sm;
  }
  __syncthreads();
  const float inv = 1.f / sred[1];
  if (tid < 128) wts[tid] = v * inv;
  __syncthreads();
#pragma unroll
  for (int kk = 0; kk < 4; ++kk) {
    int d = tid + kk * 256;
    float a = 0.f;
    for (int ss = 0; ss < 128; ++ss)
      a += wts[ss] * enc_out[((size_t)(b * 128 + ss)) * 1024 + d];
    attn_swz[((size_t)(d >> 3) * 512 + m) * 8 + (d & 7)] = f2bf(a);
  }
}

// ---- logits = attn @ Wo ---------------------------------------------------
__global__ __launch_bounds__(256) void gemm_wo(const short* __restrict__ attn_s,
                                               const short* __restrict__ wo_s,
                                               short* logits) {
  gemm_body(attn_s, wo_s, nullptr, logits, 512, 32000, 1024,
            blockIdx.x, blockIdx.y, true);
}

// ---- row softmax over 32000 vocab, bf16 logits + bias -> fp32 probs -------
__global__ __launch_bounds__(256) void softmax_out(const short* __restrict__ logits,
                                                   const float* __restrict__ bo,
                                                   float* __restrict__ out) {
  const int m = blockIdx.x, tid = threadIdx.x;
  __shared__ float red[256];
  const short* lp = logits + (size_t)m * 32000;
  float mx = -1e30f;
  for (int n = tid; n < 32000; n += 256) mx = fmaxf(mx, b2f(lp[n]) + bo[n]);
  red[tid] = mx;
  __syncthreads();
  for (int s2 = 128; s2 > 0; s2 >>= 1) {
    if (tid < s2) red[tid] = fmaxf(red[tid], red[tid + s2]);
    __syncthreads();
  }
  const float M = red[0];
  __syncthreads();
  float sm = 0.f;
  for (int n = tid; n < 32000; n += 256) sm += __expf(b2f(lp[n]) + bo[n] - M);
  red[tid] = sm;
  __syncthreads();
  for (int s2 = 128; s2 > 0; s2 >>= 1) {
    if (tid < s2) red[tid] += red[tid + s2];
    __syncthreads();
  }
  const float inv = 1.f / red[0];
  for (int n = tid; n < 32000; n += 256)
    out[(size_t)m * 32000 + n] = __expf(b2f(lp[n]) + bo[n] - M) * inv;
}

// ---------------------------------------------------------------------------
extern "C" void kernel_launch(void* const* d_in, const int* in_sizes, int n_in,
                              void* d_out, int out_size, void* d_ws, size_t ws_size,
                              hipStream_t stream) {
  (void)in_sizes; (void)n_in; (void)out_size;
  if (ws_size < WS_NEED) return;

  const int*   input_seq  = (const int*)d_in[0];
  const int*   output_seq = (const int*)d_in[1];
  const float* enc_emb    = (const float*)d_in[2];
  const float* dec_emb    = (const float*)d_in[3];
  const float* Wx_f = (const float*)d_in[4];
  const float* Wh_f = (const float*)d_in[5];
  const float* b_f  = (const float*)d_in[6];
  const float* Wx_b = (const float*)d_in[7];
  const float* Wh_b = (const float*)d_in[8];
  const float* b_b  = (const float*)d_in[9];
  const float* Wx_d = (const float*)d_in[10];
  const float* Wh_d = (const float*)d_in[11];
  const float* b_d  = (const float*)d_in[12];
  const float* attn_scale = (const float*)d_in[13];
  const float* Wo   = (const float*)d_in[14];
  const float* bo   = (const float*)d_in[15];
  float* out = (float*)d_out;

  char* ws = (char*)d_ws;
  unsigned* hbf   = (unsigned*)(ws + OFF_HBF);
  unsigned* hbb   = (unsigned*)(ws + OFF_HBB);
  unsigned* hbd   = (unsigned*)(ws + OFF_HBD);
  short* encx     = (short*)(ws + OFF_ENCX);
  short* decx     = (short*)(ws + OFF_DECX);
  short* wxf_s    = (short*)(ws + OFF_WXF);
  short* wxb_s    = (short*)(ws + OFF_WXB);
  short* wxd_s    = (short*)(ws + OFF_WXD);
  short* wo_s     = (short*)(ws + OFF_WOS);
  float* xw_f     = (float*)(ws + OFF_XWF);
  float* xw_b     = (float*)(ws + OFF_XWB);
  float* xw_d     = (float*)(ws + OFF_XWD);
  float* enc_out  = (float*)(ws + OFF_ENCO);
  float* encT     = (float*)(ws + OFF_ENCT);
  float* dec_out  = (float*)(ws + OFF_DECO);
  short* attn_s   = (short*)(ws + OFF_ATTN);
  short* logits   = (short*)(ws + OFF_LOG);
  unsigned* elec  = (unsigned*)(ws + OFF_ELEC);   // [0..15] enc, [16..31] dec

  // No memset: 0xAA poison yields tag 0xAAAA which never matches a valid tag;
  // election counters are zeroed by prep (stream-ordered before use).

  prep<<<2304, 256, 0, stream>>>(input_seq, output_seq, enc_emb, dec_emb,
                                 Wx_f, Wx_b, Wx_d, encx, decx, wxf_s, wxb_s,
                                 wxd_s, elec);
  xw_enc_gemm<<<dim3(16, 4, 2), 256, 0, stream>>>(encx, wxf_s, wxb_s, xw_f, xw_b);
  lstm_enc_fused<<<640 + 16000, 256, 0, stream>>>(
      Wh_f, Wh_b, xw_f, xw_b, b_f, b_b, hbf, hbb, enc_out, encT,
      decx, wxd_s, xw_d, Wo, wo_s, elec);
  lstm_dec<<<512, 256, 0, stream>>>(Wh_d, xw_d, b_d, enc_out, hbd, dec_out,
                                    elec + 16);
  attention<<<512, 256, 0, stream>>>(dec_out, enc_out, encT, attn_scale, attn_s);
  gemm_wo<<<dim3(250, 4), 256, 0, stream>>>(attn_s, wo_s, logits);
  softmax_out<<<512, 256, 0, stream>>>(logits, bo, out);
}

// Round 2
// 1254.872 us; speedup vs baseline: 802.8218x; 802.8218x over previous
//
#include <hip/hip_runtime.h>

// ---------------------------------------------------------------------------
// BiLSTM seq2seq + attention + vocab softmax for MI355X (gfx950).
// B=4, T=128, E=512, H=512, D=1024, V=32000.
// Round 5: revert the failed XCD-island exchange (round 4: sc0-only visibility
// is NOT prompt -> 5 ms/step eviction-paced polls). Back to the proven
// agent-scope tagged-word protocol, plus two safe structural changes:
//  - Intra-wave gates: wfrag columns remapped so each 4-lane group holds
//    {i,f,g,o} of one unit; gates combine via __shfl, c stays in registers,
//    h publishes right after the MFMA from all 4 waves (no zb LDS round trip,
//    no single-wave serial gate section).
//  - Decoder fused into the encoder launch: enc blocks publish dec-h0 into
//    hbd (fwd units at t=127, bwd units at t=0) with the same tag protocol;
//    dec blocks preload wfrag during enc and start the moment h0 lands.
//    xw_d moved to the earlier GEMM launch (launch boundary = visibility).
// ---------------------------------------------------------------------------

typedef __attribute__((ext_vector_type(8))) short bf16x8;   // 8 bf16 = 4 VGPRs
typedef __attribute__((ext_vector_type(4))) float f32x4;

__device__ __forceinline__ short f2bf(float f) {  // RNE fp32 -> bf16
  unsigned u = __builtin_bit_cast(unsigned, f);
  u += 0x7fffu + ((u >> 16) & 1u);
  return (short)(u >> 16);
}
__device__ __forceinline__ float b2f(short s) {
  unsigned u = ((unsigned)(unsigned short)s) << 16;
  return __builtin_bit_cast(float, u);
}
__device__ __forceinline__ float sigf(float x) { return 1.f / (1.f + __expf(-x)); }
__device__ __forceinline__ float tanhf_fast(float x) {
  x = fminf(fmaxf(x, -15.f), 15.f);
  float e = __expf(2.f * x);
  return (e - 1.f) / (e + 1.f);
}

// relaxed agent-scope atomics: single coherent dword access, no cache flush.
// This is the PROVEN cross-WG exchange mechanism (round 3, 2.63us/step).
__device__ __forceinline__ unsigned ld_coh(const unsigned* p) {
  return __hip_atomic_load(p, __ATOMIC_RELAXED, __HIP_MEMORY_SCOPE_AGENT);
}
__device__ __forceinline__ void st_coh(unsigned* p, unsigned v) {
  __hip_atomic_store(p, v, __ATOMIC_RELAXED, __HIP_MEMORY_SCOPE_AGENT);
}

// ---- workspace layout -----------------------------------------------------
#define OFF_HBF   ((size_t)0)                       // enc fwd h [2][4*512] u32 tagged
#define OFF_HBB   (OFF_HBF + 2*2048*4)              // enc bwd h
#define OFF_HBD   (OFF_HBB + 2*2048*4)              // dec h [2][4*1024] u32 tagged
#define OFF_ENCX  (OFF_HBD + 2*4096*4)              // enc_x swz [64][512][8] bf16
#define OFF_DECX  (OFF_ENCX + (size_t)64*512*8*2)
#define OFF_WXF   (OFF_DECX + (size_t)64*512*8*2)   // Wx_f swz [64][2048][8]
#define OFF_WXB   (OFF_WXF + (size_t)512*2048*2)
#define OFF_WXD   (OFF_WXB + (size_t)512*2048*2)    // Wx_d swz [64][4096][8]
#define OFF_WOS   (OFF_WXD + (size_t)512*4096*2)    // Wo  swz [128][32000][8]
#define OFF_XWF   (OFF_WOS + (size_t)1024*32000*2)  // xw_f fp32 [512][2048]
#define OFF_XWB   (OFF_XWF + (size_t)512*2048*4)
#define OFF_XWD   (OFF_XWB + (size_t)512*2048*4)    // xw_d fp32 [512][4096]
#define OFF_ENCO  (OFF_XWD + (size_t)512*4096*4)    // enc_out fp32 [4][128][1024]
#define OFF_ENCT  (OFF_ENCO + (size_t)4*128*1024*4) // enc_out^T fp32 [4][1024][128]
#define OFF_DECO  (OFF_ENCT + (size_t)4*128*1024*4) // dec_out fp32 [4][128][1024]
#define OFF_ATTN  (OFF_DECO + (size_t)4*128*1024*4) // attn swz [128][512][8] bf16
#define OFF_LOG   (OFF_ATTN + (size_t)128*512*8*2)  // logits bf16 [512][32000]
#define WS_NEED   (OFF_LOG + (size_t)512*32000*2)

// ---- shared bodies --------------------------------------------------------
__device__ __forceinline__ void gather_body(const int* seq, const float* emb,
                                            short* dst, int bx, int by) {
  int m  = by * 64 + (threadIdx.x & 63);
  int e8 = bx * 4 + (threadIdx.x >> 6);
  int id = seq[m];
  const float* src = emb + (size_t)id * 512 + e8 * 8;
  bf16x8 v;
#pragma unroll
  for (int j = 0; j < 8; ++j) v[j] = f2bf(src[j]);
  *(bf16x8*)(dst + ((size_t)e8 * 512 + m) * 8) = v;
}

__device__ __forceinline__ void swz_body(const float* W, short* dst, int N,
                                         int k8, int n) {
  const float* src = W + (size_t)k8 * 8 * N + n;
  bf16x8 v;
#pragma unroll
  for (int j = 0; j < 8; ++j) v[j] = f2bf(src[(size_t)j * N]);
  *(bf16x8*)(dst + ((size_t)k8 * N + n) * 8) = v;
}

// LDS-free bf16 MFMA GEMM on [K/8][M][8]-swizzled operands; 128x128/block.
__device__ __forceinline__ void gemm_body(const short* __restrict__ A,
                                          const short* __restrict__ B,
                                          float* Cf, short* Cb,
                                          int M, int N, int K,
                                          int bx, int by, bool bf16out) {
  const int wv = threadIdx.x >> 6, lane = threadIdx.x & 63;
  const int q = lane >> 4, l15 = lane & 15;
  const int m0 = by * 128 + (wv >> 1) * 64;
  const int n0 = bx * 128 + (wv & 1) * 64;
  f32x4 acc[4][4];
#pragma unroll
  for (int i = 0; i < 4; ++i)
#pragma unroll
    for (int j = 0; j < 4; ++j) acc[i][j] = (f32x4){0.f, 0.f, 0.f, 0.f};
  const int KS = K >> 5;
  for (int ks = 0; ks < KS; ++ks) {
    const size_t k8 = (size_t)(ks * 4 + q);
    const short* Ap = A + (k8 * M + m0 + l15) * 8;
    const short* Bp = B + (k8 * N + n0 + l15) * 8;
    bf16x8 av[4], bv[4];
#pragma unroll
    for (int i = 0; i < 4; ++i) av[i] = *(const bf16x8*)(Ap + i * 128);
#pragma unroll
    for (int j = 0; j < 4; ++j) bv[j] = *(const bf16x8*)(Bp + j * 128);
#pragma unroll
    for (int i = 0; i < 4; ++i)
#pragma unroll
      for (int j = 0; j < 4; ++j)
        acc[i][j] = __builtin_amdgcn_mfma_f32_16x16x32_bf16(av[i], bv[j], acc[i][j], 0, 0, 0);
  }
#pragma unroll
  for (int i = 0; i < 4; ++i)
#pragma unroll
    for (int j = 0; j < 4; ++j)
#pragma unroll
      for (int r = 0; r < 4; ++r) {
        size_t idx = (size_t)(m0 + i * 16 + q * 4 + r) * N + (n0 + j * 16 + l15);
        if (bf16out) Cb[idx] = f2bf(acc[i][j][r]);
        else         Cf[idx] = acc[i][j][r];
      }
}

// ---- prep: both gathers + three Wx swizzles, role-dispatched --------------
__global__ __launch_bounds__(256) void prep(
    const int* __restrict__ iseq, const int* __restrict__ oseq,
    const float* __restrict__ enc_emb, const float* __restrict__ dec_emb,
    const float* __restrict__ Wx_f, const float* __restrict__ Wx_b,
    const float* __restrict__ Wx_d,
    short* encx, short* decx, short* wxf_s, short* wxb_s, short* wxd_s) {
  int bid = blockIdx.x;
  if (bid < 128)        { gather_body(iseq, enc_emb, encx, bid & 15, bid >> 4); return; }
  if (bid < 256)        { int s = bid - 128;  gather_body(oseq, dec_emb, decx, s & 15, s >> 4); return; }
  if (bid < 768)        { int s = bid - 256;  swz_body(Wx_f, wxf_s, 2048, s >> 3, (s & 7) * 256 + threadIdx.x); return; }
  if (bid < 1280)       { int s = bid - 768;  swz_body(Wx_b, wxb_s, 2048, s >> 3, (s & 7) * 256 + threadIdx.x); return; }
  { int s = bid - 1280; swz_body(Wx_d, wxd_s, 4096, s >> 4, (s & 15) * 256 + threadIdx.x); }
}

// ---- all three xw GEMMs in one launch (xw_d here so the launch boundary ---
// ---- makes it visible to the fused decoder with plain loads) --------------
__global__ __launch_bounds__(256) void xw_all_gemm(
    const short* __restrict__ encx, const short* __restrict__ wxf_s,
    const short* __restrict__ wxb_s, float* xw_f, float* xw_b,
    const short* __restrict__ decx, const short* __restrict__ wxd_s,
    float* xw_d) {
  int bid = blockIdx.x;
  if (bid < 64)       { gemm_body(encx, wxf_s, xw_f, nullptr, 512, 2048, 512, bid & 15, bid >> 4, false); return; }
  if (bid < 128)      { int s = bid - 64;  gemm_body(encx, wxb_s, xw_b, nullptr, 512, 2048, 512, s & 15, s >> 4, false); return; }
  { int g = bid - 128; gemm_body(decx, wxd_s, xw_d, nullptr, 512, 4096, 512, g & 31, g >> 5, false); }
}

// ---- encoder LSTM block: intra-wave gates, c in registers -----------------
// Column map: wave w, lane l15 -> gate = l15&3, unit = u0 + w*4 + (l15>>2).
// After MFMA, q==0 lane holds z[gate][batch r][unit]; 16 shuffles gather all
// four gates per unit; each lane publishes batch b == its gate index.
__device__ __forceinline__ void lstm_enc_block(
    const float* __restrict__ Wh_f, const float* __restrict__ Wh_b,
    const float* __restrict__ xw_f, const float* __restrict__ xw_b,
    const float* __restrict__ b_f, const float* __restrict__ b_b,
    unsigned* hb_f, unsigned* hb_b, unsigned* hbd,
    float* enc_out, float* encT, int slice) {
  const int dir = slice >> 5;
  const int u0  = (slice & 31) * 16;
  const int tid = threadIdx.x;
  const int w = tid >> 6, lane = tid & 63;
  const int q = lane >> 4, l15 = lane & 15;
  const int gate = l15 & 3, du = l15 >> 2;
  const int unit = u0 + w * 4 + du;              // [0,512)
  const float* Wh   = dir ? Wh_b : Wh_f;
  const float* xw   = dir ? xw_b : xw_f;
  const float* bias = dir ? b_b : b_f;
  unsigned* hb = dir ? hb_b : hb_f;

  __shared__ __align__(16) short hs[5][520];      // h staged bf16; row 4 = zeros
  if (q == 0)  // publish h0 = 0, tag 1 (parity 0) EARLY so peers' polls pass
    st_coh(hb + gate * 512 + unit, 1u << 16);
  for (int k = tid; k < 520; k += 256) hs[4][k] = 0;

  const int col = gate * 512 + unit;             // gate-major column in [0,2048)
  const float bcol = bias[col];
  bf16x8 wfrag[16];                               // Wh fragments, live in VGPRs
#pragma unroll
  for (int ks = 0; ks < 16; ++ks) {
    bf16x8 v;
#pragma unroll
    for (int jj = 0; jj < 8; ++jj) {
      int k = ks * 32 + q * 8 + jj;
      v[jj] = f2bf(Wh[(size_t)k * 2048 + col]);
    }
    wfrag[ks] = v;
  }
  const short* hp = hs[(l15 < 4) ? l15 : 4];
  float xwv[4];
  {
    int tx0 = dir ? 127 : 0;
#pragma unroll
    for (int r = 0; r < 4; ++r) xwv[r] = xw[((size_t)(r * 128 + tx0)) * 2048 + col];
  }
  float c[4] = {0.f, 0.f, 0.f, 0.f};
  __syncthreads();

#pragma unroll 1
  for (int t = 0; t < 128; ++t) {
    // batched poll: reload ALL words in parallel each round (agent scope)
    const unsigned exp_ = (unsigned)(t + 1);
    const unsigned* src = hb + (t & 1) * 2048;
    unsigned v[8];
    bool ok;
    int guard = 0;
    do {
#pragma unroll
      for (int j = 0; j < 8; ++j) v[j] = ld_coh(src + j * 256 + tid);
      ok = true;
#pragma unroll
      for (int j = 0; j < 8; ++j) ok &= ((v[j] >> 16) == exp_);
      if (!ok) __builtin_amdgcn_s_sleep(1);
    } while (!ok && ++guard < (1 << 14));
#pragma unroll
    for (int j = 0; j < 8; ++j) {
      unsigned idx = j * 256 + tid;
      hs[idx >> 9][idx & 511] = (short)(v[j] & 0xffffu);
    }
    __syncthreads();

    f32x4 a0 = (f32x4){0.f, 0.f, 0.f, 0.f}, a1 = a0;
#pragma unroll
    for (int ks = 0; ks < 16; ks += 2) {
      bf16x8 f0 = *(const bf16x8*)(hp + ks * 32 + q * 8);
      bf16x8 f1 = *(const bf16x8*)(hp + (ks + 1) * 32 + q * 8);
      a0 = __builtin_amdgcn_mfma_f32_16x16x32_bf16(f0, wfrag[ks], a0, 0, 0, 0);
      a1 = __builtin_amdgcn_mfma_f32_16x16x32_bf16(f1, wfrag[ks + 1], a1, 0, 0, 0);
    }
    const int tx = dir ? (127 - t) : t;
    // per-lane nonlinearity for this lane's gate (rows q!=0 carry zeros; their
    // results are never stored)
    float y[4];
#pragma unroll
    for (int r = 0; r < 4; ++r) {
      float z = a0[r] + a1[r] + xwv[r] + bcol;
      y[r] = (gate == 2) ? tanhf_fast(z) : sigf(z);
    }
    if (t < 127) {                      // prefetch next xw under the shuffles
      int txn = dir ? (126 - t) : (t + 1);
#pragma unroll
      for (int r = 0; r < 4; ++r) xwv[r] = xw[((size_t)(r * 128 + txn)) * 2048 + col];
    }
    const int gb = lane & ~3;
    float yi[4], yf[4], yg[4], yo[4];
#pragma unroll
    for (int r = 0; r < 4; ++r) {
      yi[r] = __shfl(y[r], gb);
      yf[r] = __shfl(y[r], gb + 1);
      yg[r] = __shfl(y[r], gb + 2);
      yo[r] = __shfl(y[r], gb + 3);
    }
#pragma unroll
    for (int r = 0; r < 4; ++r) c[r] = yf[r] * c[r] + yi[r] * yg[r];
    // select this lane's batch (b == gate) without runtime array indexing
    float cg = c[0], yog = yo[0];
    cg  = (gate == 1) ? c[1]  : cg;  cg  = (gate == 2) ? c[2]  : cg;  cg  = (gate == 3) ? c[3]  : cg;
    yog = (gate == 1) ? yo[1] : yog; yog = (gate == 2) ? yo[2] : yog; yog = (gate == 3) ? yo[3] : yog;
    const float hv = yog * tanhf_fast(cg);
    if (q == 0) {
      const int b = gate, d = dir * 512 + unit;
      const unsigned short hb16 = (unsigned short)f2bf(hv);
      if (t < 127)
        st_coh(hb + ((t + 1) & 1) * 2048 + b * 512 + unit,
               ((unsigned)(t + 2) << 16) | hb16);
      if ((dir == 0 && t == 127) || (dir == 1 && t == 0))   // dec h0 publish
        st_coh(hbd + b * 1024 + d, (1u << 16) | hb16);
      enc_out[((size_t)(b * 128 + tx)) * 1024 + d] = hv;
      encT[((size_t)(b * 1024 + d)) * 128 + tx] = hv;
    }
    __syncthreads();   // protect hs against next iteration's staging
  }
}

// ---- decoder LSTM block (same structure; D=1024, waits on hbd) ------------
__device__ __forceinline__ void lstm_dec_block(
    const float* __restrict__ Wh_d, const float* __restrict__ xw_d,
    const float* __restrict__ b_d, unsigned* hb, float* dec_out, int slice) {
  const int u0  = slice * 16;
  const int tid = threadIdx.x;
  const int w = tid >> 6, lane = tid & 63;
  const int q = lane >> 4, l15 = lane & 15;
  const int gate = l15 & 3, du = l15 >> 2;
  const int unit = u0 + w * 4 + du;              // [0,1024)

  __shared__ __align__(16) short hs[5][1032];     // row 4 = zeros
  for (int k = tid; k < 1032; k += 256) hs[4][k] = 0;

  const int col = gate * 1024 + unit;            // [0,4096)
  const float bcol = b_d[col];
  bf16x8 wfrag[32];                               // preloaded DURING enc phase
#pragma unroll
  for (int ks = 0; ks < 32; ++ks) {
    bf16x8 v;
#pragma unroll
    for (int jj = 0; jj < 8; ++jj) {
      int k = ks * 32 + q * 8 + jj;
      v[jj] = f2bf(Wh_d[(size_t)k * 4096 + col]);
    }
    wfrag[ks] = v;
  }
  const short* hp = hs[(l15 < 4) ? l15 : 4];
  float xwv[4];
#pragma unroll
  for (int r = 0; r < 4; ++r) xwv[r] = xw_d[((size_t)(r * 128)) * 4096 + col];
  float c[4] = {0.f, 0.f, 0.f, 0.f};

  // cheap pre-gate: one dword poll until enc fwd h(127) starts landing, so the
  // heavy 16-word poll doesn't hammer MALL for ~330us while enc runs.
  if (tid == 0) {
    int g = 0;
    while ((ld_coh(hb) >> 16) != 1u && ++g < (1 << 14)) __builtin_amdgcn_s_sleep(64);
  }
  __syncthreads();

#pragma unroll 1
  for (int t = 0; t < 128; ++t) {
    const unsigned exp_ = (unsigned)(t + 1);
    const unsigned* src = hb + (t & 1) * 4096;
    unsigned v[16];
    bool ok;
    int guard = 0;
    do {
#pragma unroll
      for (int j = 0; j < 16; ++j) v[j] = ld_coh(src + j * 256 + tid);
      ok = true;
#pragma unroll
      for (int j = 0; j < 16; ++j) ok &= ((v[j] >> 16) == exp_);
      if (!ok) __builtin_amdgcn_s_sleep(1);
    } while (!ok && ++guard < (1 << 14));
#pragma unroll
    for (int j = 0; j < 16; ++j) {
      unsigned idx = j * 256 + tid;
      hs[idx >> 10][idx & 1023] = (short)(v[j] & 0xffffu);
    }
    __syncthreads();

    f32x4 a0 = (f32x4){0.f, 0.f, 0.f, 0.f}, a1 = a0;
#pragma unroll
    for (int ks = 0; ks < 32; ks += 2) {
      bf16x8 f0 = *(const bf16x8*)(hp + ks * 32 + q * 8);
      bf16x8 f1 = *(const bf16x8*)(hp + (ks + 1) * 32 + q * 8);
      a0 = __builtin_amdgcn_mfma_f32_16x16x32_bf16(f0, wfrag[ks], a0, 0, 0, 0);
      a1 = __builtin_amdgcn_mfma_f32_16x16x32_bf16(f1, wfrag[ks + 1], a1, 0, 0, 0);
    }
    float y[4];
#pragma unroll
    for (int r = 0; r < 4; ++r) {
      float z = a0[r] + a1[r] + xwv[r] + bcol;
      y[r] = (gate == 2) ? tanhf_fast(z) : sigf(z);
    }
    if (t < 127) {
#pragma unroll
      for (int r = 0; r < 4; ++r) xwv[r] = xw_d[((size_t)(r * 128 + t + 1)) * 4096 + col];
    }
    const int gb = lane & ~3;
    float yi[4], yf[4], yg[4], yo[4];
#pragma unroll
    for (int r = 0; r < 4; ++r) {
      yi[r] = __shfl(y[r], gb);
      yf[r] = __shfl(y[r], gb + 1);
      yg[r] = __shfl(y[r], gb + 2);
      yo[r] = __shfl(y[r], gb + 3);
    }
#pragma unroll
    for (int r = 0; r < 4; ++r) c[r] = yf[r] * c[r] + yi[r] * yg[r];
    float cg = c[0], yog = yo[0];
    cg  = (gate == 1) ? c[1]  : cg;  cg  = (gate == 2) ? c[2]  : cg;  cg  = (gate == 3) ? c[3]  : cg;
    yog = (gate == 1) ? yo[1] : yog; yog = (gate == 2) ? yo[2] : yog; yog = (gate == 3) ? yo[3] : yog;
    const float hv = yog * tanhf_fast(cg);
    if (q == 0) {
      const int b = gate;
      if (t < 127)
        st_coh(hb + ((t + 1) & 1) * 4096 + b * 1024 + unit,
               ((unsigned)(t + 2) << 16) | (unsigned short)f2bf(hv));
      dec_out[((size_t)(b * 128 + t)) * 1024 + unit] = hv;
    }
    __syncthreads();
  }
}

// ---- fused LSTM launch: enc (0..63) + dec (64..127) + Wo swizzle ----------
__global__ __launch_bounds__(256, 1) void lstm_fused(
    const float* __restrict__ Wh_f, const float* __restrict__ Wh_b,
    const float* __restrict__ xw_f, const float* __restrict__ xw_b,
    const float* __restrict__ b_f, const float* __restrict__ b_b,
    unsigned* hb_f, unsigned* hb_b, unsigned* hbd, float* enc_out, float* encT,
    const float* __restrict__ Wh_d, const float* __restrict__ xw_d,
    const float* __restrict__ b_d, float* dec_out,
    const float* __restrict__ Wo, short* wo_s) {
  const int bid = blockIdx.x;
  if (bid >= 128) {          // Wo swizzle: 16000 blocks, N=32000, 128 k8-rows
    int sb = bid - 128;
    int k8 = sb / 125, nb = sb - k8 * 125;
    swz_body(Wo, wo_s, 32000, k8, nb * 256 + threadIdx.x);
    return;
  }
  if (bid >= 64) {           // decoder (waits on hbd tags published by enc)
    lstm_dec_block(Wh_d, xw_d, b_d, hbd, dec_out, bid - 64);
    return;
  }
  lstm_enc_block(Wh_f, Wh_b, xw_f, xw_b, b_f, b_b, hb_f, hb_b, hbd,
                 enc_out, encT, bid);
}

// ---- attention: one block per (b,t); writes swizzled bf16 attn ------------
__global__ __launch_bounds__(256) void attention(
    const float* __restrict__ dec_out, const float* __restrict__ enc_out,
    const float* __restrict__ encT, const float* __restrict__ scale,
    short* __restrict__ attn_swz) {
  const int m = blockIdx.x, b = m >> 7, tid = threadIdx.x;
  __shared__ float dec_s[1024], scl_s[1024];
  __shared__ float red[256], wts[128], sred[2];
  for (int d = tid; d < 1024; d += 256) {
    dec_s[d] = dec_out[(size_t)m * 1024 + d];
    scl_s[d] = scale[d];
  }
  __syncthreads();
  const int s = tid & 127, half = tid >> 7;
  float sc = 0.f;
  const float* ep = encT + (size_t)b * 1024 * 128 + s;
  for (int d = half * 512; d < half * 512 + 512; ++d)
    sc += tanhf_fast(dec_s[d] + ep[(size_t)d * 128]) * scl_s[d];
  red[tid] = sc;
  __syncthreads();
  float v = 0.f;
  if (tid < 128) { v = red[tid] + red[tid + 128]; wts[tid] = v; }
  __syncthreads();
  if (tid < 64) {
    float mx = fmaxf(wts[tid], wts[tid + 64]);
    for (int off = 32; off; off >>= 1) mx = fmaxf(mx, __shfl_down(mx, off));
    if (tid == 0) sred[0] = mx;
  }
  __syncthreads();
  const float MX = sred[0];
  if (tid < 128) { v = __expf(v - MX); wts[tid] = v; }
  __syncthreads();
  if (tid < 64) {
    float sm = wts[tid] + wts[tid + 64];
    for (int off = 32; off; off >>= 1) sm += __shfl_down(sm, off);
    if (tid == 0) sred[1] = sm;
  }
  __syncthreads();
  const float inv = 1.f / sred[1];
  if (tid < 128) wts[tid] = v * inv;
  __syncthreads();
#pragma unroll
  for (int kk = 0; kk < 4; ++kk) {
    int d = tid + kk * 256;
    float a = 0.f;
    for (int ss = 0; ss < 128; ++ss)
      a += wts[ss] * enc_out[((size_t)(b * 128 + ss)) * 1024 + d];
    attn_swz[((size_t)(d >> 3) * 512 + m) * 8 + (d & 7)] = f2bf(a);
  }
}

// ---- logits = attn @ Wo ---------------------------------------------------
__global__ __launch_bounds__(256) void gemm_wo(const short* __restrict__ attn_s,
                                               const short* __restrict__ wo_s,
                                               short* logits) {
  gemm_body(attn_s, wo_s, nullptr, logits, 512, 32000, 1024,
            blockIdx.x, blockIdx.y, true);
}

// ---- row softmax over 32000 vocab, bf16 logits + bias -> fp32 probs -------
__global__ __launch_bounds__(256) void softmax_out(const short* __restrict__ logits,
                                                   const float* __restrict__ bo,
                                                   float* __restrict__ out) {
  const int m = blockIdx.x, tid = threadIdx.x;
  __shared__ float red[256];
  const short* lp = logits + (size_t)m * 32000;
  float mx = -1e30f;
  for (int n = tid; n < 32000; n += 256) mx = fmaxf(mx, b2f(lp[n]) + bo[n]);
  red[tid] = mx;
  __syncthreads();
  for (int s2 = 128; s2 > 0; s2 >>= 1) {
    if (tid < s2) red[tid] = fmaxf(red[tid], red[tid + s2]);
    __syncthreads();
  }
  const float M = red[0];
  __syncthreads();
  float sm = 0.f;
  for (int n = tid; n < 32000; n += 256) sm += __expf(b2f(lp[n]) + bo[n] - M);
  red[tid] = sm;
  __syncthreads();
  for (int s2 = 128; s2 > 0; s2 >>= 1) {
    if (tid < s2) red[tid] += red[tid + s2];
    __syncthreads();
  }
  const float inv = 1.f / red[0];
  for (int n = tid; n < 32000; n += 256)
    out[(size_t)m * 32000 + n] = __expf(b2f(lp[n]) + bo[n] - M) * inv;
}

// ---------------------------------------------------------------------------
extern "C" void kernel_launch(void* const* d_in, const int* in_sizes, int n_in,
                              void* d_out, int out_size, void* d_ws, size_t ws_size,
                              hipStream_t stream) {
  (void)in_sizes; (void)n_in; (void)out_size;
  if (ws_size < WS_NEED) return;

  const int*   input_seq  = (const int*)d_in[0];
  const int*   output_seq = (const int*)d_in[1];
  const float* enc_emb    = (const float*)d_in[2];
  const float* dec_emb    = (const float*)d_in[3];
  const float* Wx_f = (const float*)d_in[4];
  const float* Wh_f = (const float*)d_in[5];
  const float* b_f  = (const float*)d_in[6];
  const float* Wx_b = (const float*)d_in[7];
  const float* Wh_b = (const float*)d_in[8];
  const float* b_b  = (const float*)d_in[9];
  const float* Wx_d = (const float*)d_in[10];
  const float* Wh_d = (const float*)d_in[11];
  const float* b_d  = (const float*)d_in[12];
  const float* attn_scale = (const float*)d_in[13];
  const float* Wo   = (const float*)d_in[14];
  const float* bo   = (const float*)d_in[15];
  float* out = (float*)d_out;

  char* ws = (char*)d_ws;
  unsigned* hbf   = (unsigned*)(ws + OFF_HBF);
  unsigned* hbb   = (unsigned*)(ws + OFF_HBB);
  unsigned* hbd   = (unsigned*)(ws + OFF_HBD);
  short* encx     = (short*)(ws + OFF_ENCX);
  short* decx     = (short*)(ws + OFF_DECX);
  short* wxf_s    = (short*)(ws + OFF_WXF);
  short* wxb_s    = (short*)(ws + OFF_WXB);
  short* wxd_s    = (short*)(ws + OFF_WXD);
  short* wo_s     = (short*)(ws + OFF_WOS);
  float* xw_f     = (float*)(ws + OFF_XWF);
  float* xw_b     = (float*)(ws + OFF_XWB);
  float* xw_d     = (float*)(ws + OFF_XWD);
  float* enc_out  = (float*)(ws + OFF_ENCO);
  float* encT     = (float*)(ws + OFF_ENCT);
  float* dec_out  = (float*)(ws + OFF_DECO);
  short* attn_s   = (short*)(ws + OFF_ATTN);
  short* logits   = (short*)(ws + OFF_LOG);

  // No memset: 0xAA poison yields tag 0xAAAA which never matches a valid tag.

  prep<<<2304, 256, 0, stream>>>(input_seq, output_seq, enc_emb, dec_emb,
                                 Wx_f, Wx_b, Wx_d, encx, decx, wxf_s, wxb_s, wxd_s);
  xw_all_gemm<<<256, 256, 0, stream>>>(encx, wxf_s, wxb_s, xw_f, xw_b,
                                       decx, wxd_s, xw_d);
  lstm_fused<<<128 + 16000, 256, 0, stream>>>(
      Wh_f, Wh_b, xw_f, xw_b, b_f, b_b, hbf, hbb, hbd, enc_out, encT,
      Wh_d, xw_d, b_d, dec_out, Wo, wo_s);
  attention<<<512, 256, 0, stream>>>(dec_out, enc_out, encT, attn_scale, attn_s);
  gemm_wo<<<dim3(250, 4), 256, 0, stream>>>(attn_s, wo_s, logits);
  softmax_out<<<512, 256, 0, stream>>>(logits, bo, out);
}